// Round 4
// baseline (600.711 us; speedup 1.0000x reference)
//
#include <hip/hip_runtime.h>
#include <hip/hip_bf16.h>
#include <stdint.h>

#define B_ 4
#define S_ 2048
#define D_ 1024
#define M_ 4

typedef __bf16 bf16;
typedef __bf16 bf16x8 __attribute__((ext_vector_type(8)));
typedef float f32x4 __attribute__((ext_vector_type(4)));

// fp32 -> bf16 vector copy (inputs are fp32 per reference; MFMA needs bf16)
__global__ __launch_bounds__(256) void convert_copy(const float* __restrict__ in,
                                                    bf16* __restrict__ out, long n) {
  const long i = ((long)blockIdx.x * blockDim.x + threadIdx.x) * 8;
  if (i >= n) return;
  const float4 a = *(const float4*)(in + i);
  const float4 b = *(const float4*)(in + i + 4);
  bf16x8 o;
  o[0] = (bf16)a.x; o[1] = (bf16)a.y; o[2] = (bf16)a.z; o[3] = (bf16)a.w;
  o[4] = (bf16)b.x; o[5] = (bf16)b.y; o[6] = (bf16)b.z; o[7] = (bf16)b.w;
  *(bf16x8*)(out + i) = o;
}

// W [1024,1024] fp32 -> WT [1024,1024] bf16
__global__ __launch_bounds__(256) void transposeW(const float* __restrict__ in,
                                                  bf16* __restrict__ out) {
  __shared__ bf16 t[64][65];
  const int r0 = blockIdx.y * 64;
  const int c0 = blockIdx.x * 64;
  const int tx = threadIdx.x & 63;
  const int ty = threadIdx.x >> 6;
#pragma unroll
  for (int i = ty; i < 64; i += 4)
    t[i][tx] = (bf16)in[(long)(r0 + i) * D_ + c0 + tx];
  __syncthreads();
#pragma unroll
  for (int i = ty; i < 64; i += 4) out[(long)(c0 + i) * D_ + r0 + tx] = t[tx][i];
}

// C[m,n] = alpha * sum_k A[m,k] * Bt[n,k] + bias[n]   (bias fp32, epilogue fp32)
// 128x128 tile, BK=64, register->LDS staging, 4 waves 2x2, 4x4 frags of
// mfma_f32_16x16x32_bf16. TRANSV: scatter C into [B][D][S] (row = b*2048+s).
template <typename OutT, bool TRANSV>
__global__ __launch_bounds__(256) void gemm_bt(
    const bf16* __restrict__ A, int lda,
    const bf16* __restrict__ Bt, int ldb,
    OutT* __restrict__ C, int ldc,
    const float* __restrict__ bias, float alpha, int K) {
  __shared__ __align__(16) bf16 As[128 * 72];  // +8 pad kills frag-read conflicts
  __shared__ __align__(16) bf16 Bs[128 * 72];
  const int tid = threadIdx.x;
  const int lane = tid & 63;
  const int w = tid >> 6;
  const int wm = w & 1;
  const int wn = w >> 1;
  const int row0 = blockIdx.y * 128;
  const int col0 = blockIdx.x * 128;
  const int quad = lane >> 4;
  const int l15 = lane & 15;
  const int srow = tid >> 3;       // 0..31 (row within 32-row chunk)
  const int scol = (tid & 7) * 8;  // 0..56, 8 bf16 = 16B per thread

  f32x4 acc[4][4];
#pragma unroll
  for (int i = 0; i < 4; ++i)
#pragma unroll
    for (int j = 0; j < 4; ++j) acc[i][j] = (f32x4){0.f, 0.f, 0.f, 0.f};

  for (int kt = 0; kt < K; kt += 64) {
    bf16x8 av[4], bvv[4];
#pragma unroll
    for (int c = 0; c < 4; ++c) {
      av[c] = *(const bf16x8*)(A + (long)(row0 + c * 32 + srow) * lda + kt + scol);
      bvv[c] = *(const bf16x8*)(Bt + (long)(col0 + c * 32 + srow) * ldb + kt + scol);
    }
    __syncthreads();  // prior iteration's frag reads done before overwrite
#pragma unroll
    for (int c = 0; c < 4; ++c) {
      *(bf16x8*)&As[(c * 32 + srow) * 72 + scol] = av[c];
      *(bf16x8*)&Bs[(c * 32 + srow) * 72 + scol] = bvv[c];
    }
    __syncthreads();
#pragma unroll
    for (int ks = 0; ks < 2; ++ks) {
      bf16x8 af[4], bf[4];
#pragma unroll
      for (int i = 0; i < 4; ++i) {
        // A frag: A[m = lane&15][k = quad*8 + j]  (m89/m120-verified layout)
        af[i] = *(const bf16x8*)&As[(wm * 64 + i * 16 + l15) * 72 + ks * 32 + quad * 8];
        bf[i] = *(const bf16x8*)&Bs[(wn * 64 + i * 16 + l15) * 72 + ks * 32 + quad * 8];
      }
#pragma unroll
      for (int mi = 0; mi < 4; ++mi)
#pragma unroll
        for (int ni = 0; ni < 4; ++ni)
          acc[mi][ni] = __builtin_amdgcn_mfma_f32_16x16x32_bf16(af[mi], bf[ni], acc[mi][ni], 0, 0, 0);
    }
  }

  // C/D layout (m89-verified): col = lane&15 (n-side), row = quad*4 + reg (m-side)
#pragma unroll
  for (int mi = 0; mi < 4; ++mi)
#pragma unroll
    for (int ni = 0; ni < 4; ++ni) {
      const int col = col0 + wn * 64 + ni * 16 + l15;
      const float bv = bias ? bias[col] : 0.0f;
#pragma unroll
      for (int r = 0; r < 4; ++r) {
        const int row = row0 + wm * 64 + mi * 16 + quad * 4 + r;
        const float val = acc[mi][ni][r] * alpha + bv;
        if (TRANSV) {
          C[((long)(row >> 11) * D_ + col) * (long)S_ + (row & (S_ - 1))] = (OutT)val;
        } else {
          C[(long)row * ldc + col] = (OutT)val;
        }
      }
    }
}

// One block per q row, single batch. P = sum_m softmax_m / M, written bf16
// in-place over the fp32 scores row (pitch 2*S bf16 elements).
__global__ __launch_bounds__(256) void softmax_combine(
    const float* __restrict__ scores, const int* __restrict__ masks,
    bf16* __restrict__ P) {
  const int q = blockIdx.x;
  const int tid = threadIdx.x;
  __shared__ float red[4];

  float s[8];
  {
    const float4* p = (const float4*)(scores + (long)q * S_ + tid * 8);
    const float4 v0 = p[0], v1 = p[1];
    s[0] = v0.x; s[1] = v0.y; s[2] = v0.z; s[3] = v0.w;
    s[4] = v1.x; s[5] = v1.y; s[6] = v1.z; s[7] = v1.w;
  }
  float acc[8];
#pragma unroll
  for (int j = 0; j < 8; ++j) acc[j] = 0.f;

  for (int m = 0; m < M_; ++m) {
    const int4* mp = (const int4*)(masks + ((long)m * S_ + q) * S_ + tid * 8);
    const int4 m0v = mp[0], m1v = mp[1];
    const int mk[8] = {m0v.x, m0v.y, m0v.z, m0v.w, m1v.x, m1v.y, m1v.z, m1v.w};
    float v[8];
    float lmax = -3.0e38f;
#pragma unroll
    for (int j = 0; j < 8; ++j) {
      v[j] = (mk[j] != 0) ? s[j] : -1.0e9f;
      lmax = fmaxf(lmax, v[j]);
    }
#pragma unroll
    for (int o = 32; o > 0; o >>= 1) lmax = fmaxf(lmax, __shfl_xor(lmax, o, 64));
    __syncthreads();
    if ((tid & 63) == 0) red[tid >> 6] = lmax;
    __syncthreads();
    const float rmax = fmaxf(fmaxf(red[0], red[1]), fmaxf(red[2], red[3]));

    float e[8];
    float lsum = 0.f;
#pragma unroll
    for (int j = 0; j < 8; ++j) {
      e[j] = __expf(v[j] - rmax);
      lsum += e[j];
    }
#pragma unroll
    for (int o = 32; o > 0; o >>= 1) lsum += __shfl_xor(lsum, o, 64);
    __syncthreads();
    if ((tid & 63) == 0) red[tid >> 6] = lsum;
    __syncthreads();
    const float rinv = 1.0f / (red[0] + red[1] + red[2] + red[3]);
#pragma unroll
    for (int j = 0; j < 8; ++j) acc[j] += e[j] * rinv;
  }

  bf16x8 o;
#pragma unroll
  for (int j = 0; j < 8; ++j) o[j] = (bf16)(acc[j] * 0.25f);
  *(bf16x8*)(P + (long)q * (2 * S_) + tid * 8) = o;
}

extern "C" void kernel_launch(void* const* d_in, const int* in_sizes, int n_in,
                              void* d_out, int out_size, void* d_ws, size_t ws_size,
                              hipStream_t stream) {
  const float* x = (const float*)d_in[0];
  const int* masks = (const int*)d_in[1];
  const float* bq = (const float*)d_in[3];
  const float* bk = (const float*)d_in[5];
  const float* bv = (const float*)d_in[7];
  const float* bo = (const float*)d_in[9];
  float* out = (float*)d_out;  // reference output dtype is fp32

  const long DD = (long)D_ * D_;
  const long SD = (long)S_ * D_;
  const long NX = (long)B_ * SD;

  // ws: xc 16M | WT 4x2M | Q 16M | K 16M | VT 16M | scores 16M  = 88 MiB
  bf16* xc = (bf16*)d_ws;
  bf16* WqT = xc + NX;
  bf16* WkT = WqT + DD;
  bf16* WvT = WkT + DD;
  bf16* WoT = WvT + DD;
  bf16* Q = WoT + DD;
  bf16* K = Q + NX;
  bf16* VT = K + NX;
  float* scores = (float*)(VT + NX);  // per-batch, reused
  bf16* P = (bf16*)scores;            // in-place, pitch 2*S
  bf16* attn = Q;                     // attn_b overwrites dead Q_b

  dim3 blk(256);

  convert_copy<<<dim3((uint32_t)(NX / 8 / 256)), blk, 0, stream>>>(x, xc, NX);
  transposeW<<<dim3(16, 16), blk, 0, stream>>>((const float*)d_in[2], WqT);
  transposeW<<<dim3(16, 16), blk, 0, stream>>>((const float*)d_in[4], WkT);
  transposeW<<<dim3(16, 16), blk, 0, stream>>>((const float*)d_in[6], WvT);
  transposeW<<<dim3(16, 16), blk, 0, stream>>>((const float*)d_in[8], WoT);

  // Q/K = x @ W + b : [8192,1024] x [1024,1024]; V written transposed [B][D][S]
  gemm_bt<bf16, false><<<dim3(8, 64), blk, 0, stream>>>(
      xc, D_, WqT, D_, Q, D_, bq, 1.0f, D_);
  gemm_bt<bf16, false><<<dim3(8, 64), blk, 0, stream>>>(
      xc, D_, WkT, D_, K, D_, bk, 1.0f, D_);
  gemm_bt<bf16, true><<<dim3(8, 64), blk, 0, stream>>>(
      xc, D_, WvT, D_, VT, S_, bv, 1.0f, D_);

  for (int b = 0; b < B_; ++b) {
    // scores_b = Q_b K_b^T / 32 : [2048,2048] fp32
    gemm_bt<float, false><<<dim3(16, 16), blk, 0, stream>>>(
        Q + b * SD, D_, K + b * SD, D_, scores, S_, nullptr, 1.0f / 32.0f, D_);
    // P_b = (sum_m softmax_m(masked scores_b)) / M, bf16 in-place
    softmax_combine<<<dim3(S_), blk, 0, stream>>>(scores, masks, P);
    // attn_b = P_b @ V_b : [2048,1024], K=2048 (overwrites dead Q_b)
    gemm_bt<bf16, false><<<dim3(8, 16), blk, 0, stream>>>(
        P, 2 * S_, VT + b * SD, S_, attn + b * SD, D_, nullptr, 1.0f, S_);
  }

  // out = attn @ Wo + bo : [8192,1024] x [1024,1024], fp32 epilogue to d_out
  gemm_bt<float, false><<<dim3(8, 64), blk, 0, stream>>>(
      attn, D_, WoT, D_, out, D_, bo, 1.0f, D_);
}

// Round 5
// 434.584 us; speedup vs baseline: 1.3823x; 1.3823x over previous
//
#include <hip/hip_runtime.h>
#include <hip/hip_bf16.h>
#include <stdint.h>

#define B_ 4
#define S_ 2048
#define D_ 1024
#define M_ 4

typedef __bf16 bf16;
typedef __bf16 bf16x8 __attribute__((ext_vector_type(8)));
typedef float f32x4 __attribute__((ext_vector_type(4)));

__device__ __forceinline__ void async_copy16(const void* g, void* l) {
  __builtin_amdgcn_global_load_lds(
      (const __attribute__((address_space(1))) void*)g,
      (__attribute__((address_space(3))) void*)l, 16, 0, 0);
}

// fp32 -> bf16 vector copy
__global__ __launch_bounds__(256) void convert_copy(const float* __restrict__ in,
                                                    bf16* __restrict__ out, long n) {
  const long i = ((long)blockIdx.x * blockDim.x + threadIdx.x) * 8;
  if (i >= n) return;
  const float4 a = *(const float4*)(in + i);
  const float4 b = *(const float4*)(in + i + 4);
  bf16x8 o;
  o[0] = (bf16)a.x; o[1] = (bf16)a.y; o[2] = (bf16)a.z; o[3] = (bf16)a.w;
  o[4] = (bf16)b.x; o[5] = (bf16)b.y; o[6] = (bf16)b.z; o[7] = (bf16)b.w;
  *(bf16x8*)(out + i) = o;
}

// 4x W [1024,1024] fp32 -> WT [1024,1024] bf16 (z selects weight)
__global__ __launch_bounds__(256) void transposeW4(
    const float* __restrict__ w0, const float* __restrict__ w1,
    const float* __restrict__ w2, const float* __restrict__ w3,
    bf16* __restrict__ out) {
  __shared__ bf16 t[64][65];
  const float* in = (blockIdx.z == 0) ? w0 : (blockIdx.z == 1) ? w1
                    : (blockIdx.z == 2) ? w2 : w3;
  out += (long)blockIdx.z * D_ * D_;
  const int r0 = blockIdx.y * 64;
  const int c0 = blockIdx.x * 64;
  const int tx = threadIdx.x & 63;
  const int ty = threadIdx.x >> 6;
#pragma unroll
  for (int i = ty; i < 64; i += 4)
    t[i][tx] = (bf16)in[(long)(r0 + i) * D_ + c0 + tx];
  __syncthreads();
#pragma unroll
  for (int i = ty; i < 64; i += 4) out[(long)(c0 + i) * D_ + r0 + tx] = t[tx][i];
}

// C[m,n] = alpha * sum_k A[m,k]*Bt[n,k] + bias[n]   (m97 structure:
// 128x128 tile, BK=64, global_load_lds width-16, unpadded stride-64 LDS,
// 4 waves 2x2, 4x4 frags of mfma_f32_16x16x32_bf16)
// TRANSV: scatter C into [B][D][S] (row = b*2048+s, col = d).
template <typename OutT, bool TRANSV>
__global__ __launch_bounds__(256) void gemm_bt(
    const bf16* __restrict__ A, long aB, int lda,
    const bf16* __restrict__ Bt, long bB, int ldb,
    OutT* __restrict__ C, long cB, int ldc,
    const float* __restrict__ bias, float alpha, int K) {
  __shared__ __align__(16) bf16 As[128 * 64];
  __shared__ __align__(16) bf16 Bs[128 * 64];
  const int tid = threadIdx.x;
  const int lane = tid & 63;
  const int w = tid >> 6;
  const int wm = w & 1;
  const int wn = w >> 1;
  A += (long)blockIdx.z * aB;
  Bt += (long)blockIdx.z * bB;
  if (!TRANSV) C += (long)blockIdx.z * cB;
  const int row0 = blockIdx.y * 128;
  const int col0 = blockIdx.x * 128;
  const int quad = lane >> 4;
  const int l15 = lane & 15;
  const int srow = lane >> 3;       // 0..7 within the wave's 8-row chunk
  const int scol = (lane & 7) * 8;  // 8 bf16 = 16 B per lane

  f32x4 acc[4][4];
#pragma unroll
  for (int i = 0; i < 4; ++i)
#pragma unroll
    for (int j = 0; j < 4; ++j) acc[i][j] = (f32x4){0.f, 0.f, 0.f, 0.f};

  for (int kt = 0; kt < K; kt += 64) {
#pragma unroll
    for (int c = 0; c < 4; ++c) {
      const int r = c * 32 + w * 8;  // wave-uniform LDS base (8 rows = 1 KiB)
      async_copy16(A + (long)(row0 + r + srow) * lda + kt + scol, &As[r * 64]);
      async_copy16(Bt + (long)(col0 + r + srow) * ldb + kt + scol, &Bs[r * 64]);
    }
    __syncthreads();  // drains vmcnt(0): staging visible to all waves
#pragma unroll
    for (int ks = 0; ks < 2; ++ks) {
      bf16x8 af[4], bf[4];
#pragma unroll
      for (int i = 0; i < 4; ++i) {
        // A frag: A[m = lane&15][k = quad*8 + j]
        af[i] = *(const bf16x8*)&As[(wm * 64 + i * 16 + l15) * 64 + ks * 32 + quad * 8];
        bf[i] = *(const bf16x8*)&Bs[(wn * 64 + i * 16 + l15) * 64 + ks * 32 + quad * 8];
      }
#pragma unroll
      for (int mi = 0; mi < 4; ++mi)
#pragma unroll
        for (int ni = 0; ni < 4; ++ni)
          acc[mi][ni] = __builtin_amdgcn_mfma_f32_16x16x32_bf16(af[mi], bf[ni], acc[mi][ni], 0, 0, 0);
    }
    __syncthreads();  // frag reads done before next staging overwrites
  }

  // C/D layout: col = lane&15 (n-side), row = quad*4 + reg (m-side)
#pragma unroll
  for (int mi = 0; mi < 4; ++mi)
#pragma unroll
    for (int ni = 0; ni < 4; ++ni) {
      const int col = col0 + wn * 64 + ni * 16 + l15;
      const float bv = bias ? bias[col] : 0.0f;
#pragma unroll
      for (int r = 0; r < 4; ++r) {
        const int row = row0 + wm * 64 + mi * 16 + quad * 4 + r;
        const float val = acc[mi][ni][r] * alpha + bv;
        if (TRANSV) {
          C[((long)(row >> 11) * D_ + col) * (long)S_ + (row & (S_ - 1))] = (OutT)val;
        } else {
          C[(long)row * ldc + col] = (OutT)val;
        }
      }
    }
}

// grid (S, B): P[b,q,:] = (sum_m softmax_m(masked scores[b,q,:])) / M, bf16.
__global__ __launch_bounds__(256) void softmax_combine(
    const float* __restrict__ scores, const int* __restrict__ masks,
    bf16* __restrict__ P) {
  const int q = blockIdx.x;
  const int b = blockIdx.y;
  const int tid = threadIdx.x;
  __shared__ float red[4];

  float s[8];
  {
    const float4* p = (const float4*)(scores + ((long)b * S_ + q) * S_ + tid * 8);
    const float4 v0 = p[0], v1 = p[1];
    s[0] = v0.x; s[1] = v0.y; s[2] = v0.z; s[3] = v0.w;
    s[4] = v1.x; s[5] = v1.y; s[6] = v1.z; s[7] = v1.w;
  }
  float acc[8];
#pragma unroll
  for (int j = 0; j < 8; ++j) acc[j] = 0.f;

  for (int m = 0; m < M_; ++m) {
    const int4* mp = (const int4*)(masks + ((long)m * S_ + q) * S_ + tid * 8);
    const int4 m0v = mp[0], m1v = mp[1];
    const int mk[8] = {m0v.x, m0v.y, m0v.z, m0v.w, m1v.x, m1v.y, m1v.z, m1v.w};
    float v[8];
    float lmax = -3.0e38f;
#pragma unroll
    for (int j = 0; j < 8; ++j) {
      v[j] = (mk[j] != 0) ? s[j] : -1.0e9f;
      lmax = fmaxf(lmax, v[j]);
    }
#pragma unroll
    for (int o = 32; o > 0; o >>= 1) lmax = fmaxf(lmax, __shfl_xor(lmax, o, 64));
    __syncthreads();
    if ((tid & 63) == 0) red[tid >> 6] = lmax;
    __syncthreads();
    const float rmax = fmaxf(fmaxf(red[0], red[1]), fmaxf(red[2], red[3]));

    float e[8];
    float lsum = 0.f;
#pragma unroll
    for (int j = 0; j < 8; ++j) {
      e[j] = __expf(v[j] - rmax);
      lsum += e[j];
    }
#pragma unroll
    for (int o = 32; o > 0; o >>= 1) lsum += __shfl_xor(lsum, o, 64);
    __syncthreads();
    if ((tid & 63) == 0) red[tid >> 6] = lsum;
    __syncthreads();
    const float rinv = 1.0f / (red[0] + red[1] + red[2] + red[3]);
#pragma unroll
    for (int j = 0; j < 8; ++j) acc[j] += e[j] * rinv;
  }

  bf16x8 o;
#pragma unroll
  for (int j = 0; j < 8; ++j) o[j] = (bf16)(acc[j] * 0.25f);
  *(bf16x8*)(P + ((long)b * S_ + q) * S_ + tid * 8) = o;
}

extern "C" void kernel_launch(void* const* d_in, const int* in_sizes, int n_in,
                              void* d_out, int out_size, void* d_ws, size_t ws_size,
                              hipStream_t stream) {
  const float* x = (const float*)d_in[0];
  const int* masks = (const int*)d_in[1];
  const float* bq = (const float*)d_in[3];
  const float* bk = (const float*)d_in[5];
  const float* bv = (const float*)d_in[7];
  const float* bo = (const float*)d_in[9];
  float* out = (float*)d_out;  // reference output dtype is fp32

  const long DD = (long)D_ * D_;
  const long SD = (long)S_ * D_;
  const long NX = (long)B_ * SD;
  const long SS = (long)S_ * S_;

  // ws (256 MiB avail): xc 16M | WT 8M | Q 16M | K 16M | VT 16M | P 32M | scores 64M
  bf16* xc = (bf16*)d_ws;
  bf16* WqT = xc + NX;
  bf16* WkT = WqT + DD;
  bf16* WvT = WkT + DD;
  bf16* WoT = WvT + DD;
  bf16* Q = WoT + DD;
  bf16* K = Q + NX;
  bf16* VT = K + NX;
  bf16* P = VT + NX;                       // [B][S][S] bf16
  float* scores = (float*)(P + (long)B_ * SS);  // [B][S][S] fp32
  bf16* attn = Q;                          // attn overwrites dead Q

  dim3 blk(256);

  convert_copy<<<dim3((uint32_t)(NX / 8 / 256)), blk, 0, stream>>>(x, xc, NX);
  transposeW4<<<dim3(16, 16, 4), blk, 0, stream>>>(
      (const float*)d_in[2], (const float*)d_in[4],
      (const float*)d_in[6], (const float*)d_in[8], WqT);

  // Q/K = x @ W + b; V written transposed into [B][D][S]
  gemm_bt<bf16, false><<<dim3(8, 64), blk, 0, stream>>>(
      xc, 0, D_, WqT, 0, D_, Q, 0, D_, bq, 1.0f, D_);
  gemm_bt<bf16, false><<<dim3(8, 64), blk, 0, stream>>>(
      xc, 0, D_, WkT, 0, D_, K, 0, D_, bk, 1.0f, D_);
  gemm_bt<bf16, true><<<dim3(8, 64), blk, 0, stream>>>(
      xc, 0, D_, WvT, 0, D_, VT, 0, S_, bv, 1.0f, D_);

  // scores = Q K^T / 32 : [B][2048][2048] fp32, batched over z
  gemm_bt<float, false><<<dim3(16, 16, B_), blk, 0, stream>>>(
      Q, SD, D_, K, SD, D_, scores, SS, S_, nullptr, 1.0f / 32.0f, D_);

  // P = (sum_m softmax_m(masked scores)) / M, bf16, batched
  softmax_combine<<<dim3(S_, B_), blk, 0, stream>>>(scores, masks, P);

  // attn = P @ V : [B][2048][1024], K=2048, batched
  gemm_bt<bf16, false><<<dim3(8, 16, B_), blk, 0, stream>>>(
      P, SS, S_, VT, SD, S_, attn, SD, D_, nullptr, 1.0f, S_);

  // out = attn @ Wo + bo : fp32 epilogue straight to d_out
  gemm_bt<float, false><<<dim3(8, 64), blk, 0, stream>>>(
      attn, 0, D_, WoT, 0, D_, out, 0, D_, bo, 1.0f, D_);
}

// Round 6
// 420.813 us; speedup vs baseline: 1.4275x; 1.0327x over previous
//
#include <hip/hip_runtime.h>
#include <hip/hip_bf16.h>
#include <stdint.h>

#define B_ 4
#define S_ 2048
#define D_ 1024
#define M_ 4

typedef __bf16 bf16;
typedef _Float16 f16;
typedef __bf16 bf16x8 __attribute__((ext_vector_type(8)));
typedef _Float16 f16x8 __attribute__((ext_vector_type(8)));
typedef float f32x4 __attribute__((ext_vector_type(4)));

__device__ __forceinline__ void async_copy16(const void* g, void* l) {
  __builtin_amdgcn_global_load_lds(
      (const __attribute__((address_space(1))) void*)g,
      (__attribute__((address_space(3))) void*)l, 16, 0, 0);
}

// fp32 -> bf16 vector copy
__global__ __launch_bounds__(256) void convert_copy(const float* __restrict__ in,
                                                    bf16* __restrict__ out, long n) {
  const long i = ((long)blockIdx.x * blockDim.x + threadIdx.x) * 8;
  if (i >= n) return;
  const float4 a = *(const float4*)(in + i);
  const float4 b = *(const float4*)(in + i + 4);
  bf16x8 o;
  o[0] = (bf16)a.x; o[1] = (bf16)a.y; o[2] = (bf16)a.z; o[3] = (bf16)a.w;
  o[4] = (bf16)b.x; o[5] = (bf16)b.y; o[6] = (bf16)b.z; o[7] = (bf16)b.w;
  *(bf16x8*)(out + i) = o;
}

// 4x W [1024,1024] fp32 -> WT [1024,1024] bf16 (z selects weight)
__global__ __launch_bounds__(256) void transposeW4(
    const float* __restrict__ w0, const float* __restrict__ w1,
    const float* __restrict__ w2, const float* __restrict__ w3,
    bf16* __restrict__ out) {
  __shared__ bf16 t[64][65];
  const float* in = (blockIdx.z == 0) ? w0 : (blockIdx.z == 1) ? w1
                    : (blockIdx.z == 2) ? w2 : w3;
  out += (long)blockIdx.z * D_ * D_;
  const int r0 = blockIdx.y * 64;
  const int c0 = blockIdx.x * 64;
  const int tx = threadIdx.x & 63;
  const int ty = threadIdx.x >> 6;
#pragma unroll
  for (int i = ty; i < 64; i += 4)
    t[i][tx] = (bf16)in[(long)(r0 + i) * D_ + c0 + tx];
  __syncthreads();
#pragma unroll
  for (int i = ty; i < 64; i += 4) out[(long)(c0 + i) * D_ + r0 + tx] = t[tx][i];
}

// [M][S][S] int32 -> [S][S] uint8 bitfield (bit m = mask_m != 0)
__global__ __launch_bounds__(256) void pack_masks(const int* __restrict__ masks,
                                                  unsigned char* __restrict__ pk) {
  const long SS = (long)S_ * S_;
  const long e = ((long)blockIdx.x * 256 + threadIdx.x) * 8;
  unsigned long long w = 0;
#pragma unroll
  for (int m = 0; m < M_; ++m) {
    const int4 a = *(const int4*)(masks + m * SS + e);
    const int4 b = *(const int4*)(masks + m * SS + e + 4);
    const int v[8] = {a.x, a.y, a.z, a.w, b.x, b.y, b.z, b.w};
#pragma unroll
    for (int j = 0; j < 8; ++j)
      w |= (unsigned long long)(v[j] != 0 ? 1u : 0u) << (8 * j + m);
  }
  *(unsigned long long*)(pk + e) = w;
}

#define MODE_PLAIN 0
#define MODE_EXP 1   // C = exp(alpha*acc), f16 out (scores -> E)
#define MODE_QKV 2   // N=3072 grouped epilogue: Q | K | V-transposed-scatter

// C[m,n] = alpha * sum_k A[m,k]*Bt[n,k] + bias[n]   (m97 structure:
// 128x128 tile, BK=64, global_load_lds width-16, unpadded stride-64 LDS,
// 4 waves 2x2, 4x4 frags of mfma_f32_16x16x32_bf16)
template <typename OutT, int MODE>
__global__ __launch_bounds__(256) void gemm_bt(
    const bf16* __restrict__ A, long aB, int lda,
    const bf16* __restrict__ Bt, long bB, int ldb,
    OutT* __restrict__ C, long cB, int ldc,
    const float* __restrict__ bias0, const float* __restrict__ bias1,
    const float* __restrict__ bias2, float alpha, int K) {
  __shared__ __align__(16) bf16 As[128 * 64];
  __shared__ __align__(16) bf16 Bs[128 * 64];
  const int tid = threadIdx.x;
  const int lane = tid & 63;
  const int w = tid >> 6;
  const int wm = w & 1;
  const int wn = w >> 1;
  A += (long)blockIdx.z * aB;
  Bt += (long)blockIdx.z * bB;
  if (MODE != MODE_QKV) C += (long)blockIdx.z * cB;
  const int row0 = blockIdx.y * 128;
  const int col0 = blockIdx.x * 128;
  const int quad = lane >> 4;
  const int l15 = lane & 15;
  const int srow = lane >> 3;       // 0..7 within the wave's 8-row chunk
  const int scol = (lane & 7) * 8;  // 8 bf16 = 16 B per lane

  f32x4 acc[4][4];
#pragma unroll
  for (int i = 0; i < 4; ++i)
#pragma unroll
    for (int j = 0; j < 4; ++j) acc[i][j] = (f32x4){0.f, 0.f, 0.f, 0.f};

  for (int kt = 0; kt < K; kt += 64) {
#pragma unroll
    for (int c = 0; c < 4; ++c) {
      const int r = c * 32 + w * 8;  // wave-uniform LDS base (8 rows = 1 KiB)
      async_copy16(A + (long)(row0 + r + srow) * lda + kt + scol, &As[r * 64]);
      async_copy16(Bt + (long)(col0 + r + srow) * ldb + kt + scol, &Bs[r * 64]);
    }
    __syncthreads();
#pragma unroll
    for (int ks = 0; ks < 2; ++ks) {
      bf16x8 af[4], bf[4];
#pragma unroll
      for (int i = 0; i < 4; ++i) {
        af[i] = *(const bf16x8*)&As[(wm * 64 + i * 16 + l15) * 64 + ks * 32 + quad * 8];
        bf[i] = *(const bf16x8*)&Bs[(wn * 64 + i * 16 + l15) * 64 + ks * 32 + quad * 8];
      }
#pragma unroll
      for (int mi = 0; mi < 4; ++mi)
#pragma unroll
        for (int ni = 0; ni < 4; ++ni)
          acc[mi][ni] = __builtin_amdgcn_mfma_f32_16x16x32_bf16(af[mi], bf[ni], acc[mi][ni], 0, 0, 0);
    }
    __syncthreads();
  }

  // QKV grouping is block-uniform: cols 0-1023 -> Q, 1024-2047 -> K, 2048-3071 -> V^T
  const int grp = (MODE == MODE_QKV) ? (blockIdx.x >> 3) : 0;
  const float* bias = (MODE == MODE_QKV)
                          ? (grp == 0 ? bias0 : grp == 1 ? bias1 : bias2)
                          : bias0;
  const long NX = (long)B_ * S_ * D_;

  // C/D layout: col = lane&15 (n-side), row = quad*4 + reg (m-side)
#pragma unroll
  for (int mi = 0; mi < 4; ++mi)
#pragma unroll
    for (int ni = 0; ni < 4; ++ni) {
      const int col = col0 + wn * 64 + ni * 16 + l15;
      const int lcol = col & (D_ - 1);
      const float bv = bias ? bias[MODE == MODE_QKV ? lcol : col] : 0.0f;
#pragma unroll
      for (int r = 0; r < 4; ++r) {
        const int row = row0 + wm * 64 + mi * 16 + quad * 4 + r;
        const float val = acc[mi][ni][r] * alpha + bv;
        if (MODE == MODE_EXP) {
          C[(long)row * ldc + col] = (OutT)__expf(val);
        } else if (MODE == MODE_QKV) {
          if (grp < 2) {
            C[grp * NX + (long)row * D_ + lcol] = (OutT)val;
          } else {  // V scatter: row = b*2048+s -> VT[b][lcol][s]
            C[2 * NX + ((long)(row >> 11) * D_ + lcol) * (long)S_ + (row & (S_ - 1))] =
                (OutT)val;
          }
        } else {
          C[(long)row * ldc + col] = (OutT)val;
        }
      }
    }
}

// grid (S, B): P[b,q,:] = E[b,q,:] * sum_m bit_m(q,:) / rowsum_m / M, bf16.
__global__ __launch_bounds__(256) void softmax_combine(
    const f16* __restrict__ E, const unsigned char* __restrict__ pk,
    bf16* __restrict__ P) {
  const int q = blockIdx.x;
  const int b = blockIdx.y;
  const int tid = threadIdx.x;
  const int lane = tid & 63;
  const int wv = tid >> 6;
  __shared__ float4 red[4];

  float e[8];
  {
    const f16x8 h = *(const f16x8*)(E + ((long)b * S_ + q) * S_ + tid * 8);
#pragma unroll
    for (int j = 0; j < 8; ++j) e[j] = (float)h[j];
  }
  const unsigned long long mb =
      *(const unsigned long long*)(pk + (long)q * S_ + tid * 8);

  float4 s = {0.f, 0.f, 0.f, 0.f};
#pragma unroll
  for (int j = 0; j < 8; ++j) {
    const unsigned bits = (unsigned)(mb >> (8 * j)) & 0xF;
    const float ev = e[j];
    if (bits & 1) s.x += ev;
    if (bits & 2) s.y += ev;
    if (bits & 4) s.z += ev;
    if (bits & 8) s.w += ev;
  }
#pragma unroll
  for (int o = 32; o > 0; o >>= 1) {
    s.x += __shfl_xor(s.x, o, 64);
    s.y += __shfl_xor(s.y, o, 64);
    s.z += __shfl_xor(s.z, o, 64);
    s.w += __shfl_xor(s.w, o, 64);
  }
  if (lane == 0) red[wv] = s;
  __syncthreads();
  const float4 t0 = red[0], t1 = red[1], t2 = red[2], t3 = red[3];
  const float r0 = 0.25f / (t0.x + t1.x + t2.x + t3.x);
  const float r1 = 0.25f / (t0.y + t1.y + t2.y + t3.y);
  const float r2 = 0.25f / (t0.z + t1.z + t2.z + t3.z);
  const float r3 = 0.25f / (t0.w + t1.w + t2.w + t3.w);

  bf16x8 o;
#pragma unroll
  for (int j = 0; j < 8; ++j) {
    const unsigned bits = (unsigned)(mb >> (8 * j)) & 0xF;
    const float wgt = ((bits & 1) ? r0 : 0.f) + ((bits & 2) ? r1 : 0.f) +
                      ((bits & 4) ? r2 : 0.f) + ((bits & 8) ? r3 : 0.f);
    o[j] = (bf16)(e[j] * wgt);
  }
  *(bf16x8*)(P + ((long)b * S_ + q) * S_ + tid * 8) = o;
}

extern "C" void kernel_launch(void* const* d_in, const int* in_sizes, int n_in,
                              void* d_out, int out_size, void* d_ws, size_t ws_size,
                              hipStream_t stream) {
  const float* x = (const float*)d_in[0];
  const int* masks = (const int*)d_in[1];
  const float* bq = (const float*)d_in[3];
  const float* bk = (const float*)d_in[5];
  const float* bv = (const float*)d_in[7];
  const float* bo = (const float*)d_in[9];
  float* out = (float*)d_out;

  const long DD = (long)D_ * D_;
  const long SD = (long)S_ * D_;
  const long NX = (long)B_ * SD;
  const long SS = (long)S_ * S_;

  // ws: xc 16M | WT 8M | Q/K/VT 48M | P 32M | E 32M | pk 4M  = 140 MiB (256 avail)
  bf16* xc = (bf16*)d_ws;
  bf16* WqT = xc + NX;  // WkT, WvT, WoT contiguous after
  bf16* WoT = WqT + 3 * DD;
  bf16* Q = WoT + DD;  // K = Q+NX, VT = K+NX (contiguous: QKV epilogue relies on it)
  bf16* K = Q + NX;
  bf16* VT = K + NX;
  bf16* P = VT + NX;                      // [B][S][S] bf16
  f16* E = (f16*)(P + (long)B_ * SS);     // [B][S][S] f16
  unsigned char* pk = (unsigned char*)(E + (long)B_ * SS);  // [S][S] u8
  bf16* attn = Q;                         // attn overwrites dead Q

  dim3 blk(256);

  convert_copy<<<dim3((uint32_t)(NX / 8 / 256)), blk, 0, stream>>>(x, xc, NX);
  transposeW4<<<dim3(16, 16, 4), blk, 0, stream>>>(
      (const float*)d_in[2], (const float*)d_in[4],
      (const float*)d_in[6], (const float*)d_in[8], WqT);
  pack_masks<<<dim3((uint32_t)(SS / 8 / 256)), blk, 0, stream>>>(masks, pk);

  // fused Q|K|V^T projection: [8192,1024] x [1024,3072]
  gemm_bt<bf16, MODE_QKV><<<dim3(24, 64), blk, 0, stream>>>(
      xc, 0, D_, WqT, 0, D_, Q, 0, D_, bq, bk, bv, 1.0f, D_);

  // E = exp(Q K^T / 32) : [B][2048][2048] f16, batched over z
  gemm_bt<f16, MODE_EXP><<<dim3(16, 16, B_), blk, 0, stream>>>(
      Q, SD, D_, K, SD, D_, E, SS, S_, nullptr, nullptr, nullptr, 1.0f / 32.0f, D_);

  // P = E * sum_m mask_m / rowsum_m / M
  softmax_combine<<<dim3(S_, B_), blk, 0, stream>>>(E, pk, P);

  // attn = P @ V : [B][2048][1024], K=2048, batched
  gemm_bt<bf16, MODE_PLAIN><<<dim3(8, 16, B_), blk, 0, stream>>>(
      P, SS, S_, VT, SD, S_, attn, SD, D_, nullptr, nullptr, nullptr, 1.0f, S_);

  // out = attn @ Wo + bo : fp32 epilogue straight to d_out
  gemm_bt<float, MODE_PLAIN><<<dim3(8, 64), blk, 0, stream>>>(
      attn, 0, D_, WoT, 0, D_, out, 0, D_, bo, nullptr, nullptr, 1.0f, D_);
}

// Round 7
// 413.225 us; speedup vs baseline: 1.4537x; 1.0184x over previous
//
#include <hip/hip_runtime.h>
#include <hip/hip_bf16.h>
#include <stdint.h>

#define B_ 4
#define S_ 2048
#define D_ 1024
#define M_ 4

typedef __bf16 bf16;
typedef _Float16 f16;
typedef __bf16 bf16x8 __attribute__((ext_vector_type(8)));
typedef _Float16 f16x8 __attribute__((ext_vector_type(8)));
typedef float f32x4 __attribute__((ext_vector_type(4)));

__device__ __forceinline__ void async_copy16(const void* g, void* l) {
  __builtin_amdgcn_global_load_lds(
      (const __attribute__((address_space(1))) void*)g,
      (__attribute__((address_space(3))) void*)l, 16, 0, 0);
}

// fp32 -> bf16 vector copy
__global__ __launch_bounds__(256) void convert_copy(const float* __restrict__ in,
                                                    bf16* __restrict__ out, long n) {
  const long i = ((long)blockIdx.x * blockDim.x + threadIdx.x) * 8;
  if (i >= n) return;
  const float4 a = *(const float4*)(in + i);
  const float4 b = *(const float4*)(in + i + 4);
  bf16x8 o;
  o[0] = (bf16)a.x; o[1] = (bf16)a.y; o[2] = (bf16)a.z; o[3] = (bf16)a.w;
  o[4] = (bf16)b.x; o[5] = (bf16)b.y; o[6] = (bf16)b.z; o[7] = (bf16)b.w;
  *(bf16x8*)(out + i) = o;
}

// 4x W [1024,1024] fp32 -> WT [1024,1024] bf16 (z selects weight)
__global__ __launch_bounds__(256) void transposeW4(
    const float* __restrict__ w0, const float* __restrict__ w1,
    const float* __restrict__ w2, const float* __restrict__ w3,
    bf16* __restrict__ out) {
  __shared__ bf16 t[64][65];
  const float* in = (blockIdx.z == 0) ? w0 : (blockIdx.z == 1) ? w1
                    : (blockIdx.z == 2) ? w2 : w3;
  out += (long)blockIdx.z * D_ * D_;
  const int r0 = blockIdx.y * 64;
  const int c0 = blockIdx.x * 64;
  const int tx = threadIdx.x & 63;
  const int ty = threadIdx.x >> 6;
#pragma unroll
  for (int i = ty; i < 64; i += 4)
    t[i][tx] = (bf16)in[(long)(r0 + i) * D_ + c0 + tx];
  __syncthreads();
#pragma unroll
  for (int i = ty; i < 64; i += 4) out[(long)(c0 + i) * D_ + r0 + tx] = t[tx][i];
}

// batched bf16 [rows,cols] -> [cols,rows] transpose (z = batch)
__global__ __launch_bounds__(256) void transposeB(
    const bf16* __restrict__ in, bf16* __restrict__ out,
    int rows, int cols, long ib, long ob) {
  __shared__ bf16 t[64][65];
  in += (long)blockIdx.z * ib;
  out += (long)blockIdx.z * ob;
  const int r0 = blockIdx.y * 64;
  const int c0 = blockIdx.x * 64;
  const int tx = threadIdx.x & 63;
  const int ty = threadIdx.x >> 6;
#pragma unroll
  for (int i = ty; i < 64; i += 4) t[i][tx] = in[(long)(r0 + i) * cols + c0 + tx];
  __syncthreads();
#pragma unroll
  for (int i = ty; i < 64; i += 4) out[(long)(c0 + i) * rows + r0 + tx] = t[tx][i];
}

// [M][S][S] int32 -> [S][S] uint8 bitfield (bit m = mask_m != 0)
__global__ __launch_bounds__(256) void pack_masks(const int* __restrict__ masks,
                                                  unsigned char* __restrict__ pk) {
  const long SS = (long)S_ * S_;
  const long e = ((long)blockIdx.x * 256 + threadIdx.x) * 8;
  unsigned long long w = 0;
#pragma unroll
  for (int m = 0; m < M_; ++m) {
    const int4 a = *(const int4*)(masks + m * SS + e);
    const int4 b = *(const int4*)(masks + m * SS + e + 4);
    const int v[8] = {a.x, a.y, a.z, a.w, b.x, b.y, b.z, b.w};
#pragma unroll
    for (int j = 0; j < 8; ++j)
      w |= (unsigned long long)(v[j] != 0 ? 1u : 0u) << (8 * j + m);
  }
  *(unsigned long long*)(pk + e) = w;
}

#define MODE_PLAIN 0
#define MODE_EXP 1   // C = exp(alpha*acc), f16 out (scores -> E)
#define MODE_QKV 2   // N=3072 grouped epilogue: Q | K | V, all coalesced

// C[m,n] = alpha * sum_k A[m,k]*Bt[n,k] + bias[n]   (m97 structure:
// 128x128 tile, BK=64, global_load_lds width-16, unpadded stride-64 LDS,
// 4 waves 2x2, 4x4 frags of mfma_f32_16x16x32_bf16)
// GROUP-8 M-swizzle: with 8-XCD round-robin dispatch each XCD sweeps one
// 128-row A-stripe across all N columns -> per-XCD L2 A reuse.
template <typename OutT, int MODE>
__global__ __launch_bounds__(256) void gemm_bt(
    const bf16* __restrict__ A, long aB, int lda,
    const bf16* __restrict__ Bt, long bB, int ldb,
    OutT* __restrict__ C, long cB, int ldc,
    const float* __restrict__ bias0, const float* __restrict__ bias1,
    const float* __restrict__ bias2, float alpha, int K) {
  __shared__ __align__(16) bf16 As[128 * 64];
  __shared__ __align__(16) bf16 Bs[128 * 64];
  const int tid = threadIdx.x;
  const int lane = tid & 63;
  const int w = tid >> 6;
  const int wm = w & 1;
  const int wn = w >> 1;
  A += (long)blockIdx.z * aB;
  Bt += (long)blockIdx.z * bB;
  if (MODE != MODE_QKV) C += (long)blockIdx.z * cB;

  // GROUP-8 swizzle (gy is always a multiple of 8 here)
  const int gx = gridDim.x;
  const int pid = blockIdx.y * gx + blockIdx.x;
  const int gsz = 8 * gx;
  const int bym = (pid / gsz) * 8 + (pid % 8);
  const int bxm = (pid % gsz) / 8;

  const int row0 = bym * 128;
  const int col0 = bxm * 128;
  const int quad = lane >> 4;
  const int l15 = lane & 15;
  const int srow = lane >> 3;       // 0..7 within the wave's 8-row chunk
  const int scol = (lane & 7) * 8;  // 8 bf16 = 16 B per lane

  f32x4 acc[4][4];
#pragma unroll
  for (int i = 0; i < 4; ++i)
#pragma unroll
    for (int j = 0; j < 4; ++j) acc[i][j] = (f32x4){0.f, 0.f, 0.f, 0.f};

  for (int kt = 0; kt < K; kt += 64) {
#pragma unroll
    for (int c = 0; c < 4; ++c) {
      const int r = c * 32 + w * 8;  // wave-uniform LDS base (8 rows = 1 KiB)
      async_copy16(A + (long)(row0 + r + srow) * lda + kt + scol, &As[r * 64]);
      async_copy16(Bt + (long)(col0 + r + srow) * ldb + kt + scol, &Bs[r * 64]);
    }
    __syncthreads();
#pragma unroll
    for (int ks = 0; ks < 2; ++ks) {
      bf16x8 af[4], bf[4];
#pragma unroll
      for (int i = 0; i < 4; ++i) {
        af[i] = *(const bf16x8*)&As[(wm * 64 + i * 16 + l15) * 64 + ks * 32 + quad * 8];
        bf[i] = *(const bf16x8*)&Bs[(wn * 64 + i * 16 + l15) * 64 + ks * 32 + quad * 8];
      }
#pragma unroll
      for (int mi = 0; mi < 4; ++mi)
#pragma unroll
        for (int ni = 0; ni < 4; ++ni)
          acc[mi][ni] = __builtin_amdgcn_mfma_f32_16x16x32_bf16(af[mi], bf[ni], acc[mi][ni], 0, 0, 0);
    }
    __syncthreads();
  }

  // QKV grouping is block-uniform: cols 0-1023 -> Q, 1024-2047 -> K, 2048-3071 -> V
  const int grp = (MODE == MODE_QKV) ? (bxm >> 3) : 0;
  const float* bias = (MODE == MODE_QKV)
                          ? (grp == 0 ? bias0 : grp == 1 ? bias1 : bias2)
                          : bias0;
  const long NX = (long)B_ * S_ * D_;

  // C/D layout: col = lane&15 (n-side), row = quad*4 + reg (m-side)
#pragma unroll
  for (int mi = 0; mi < 4; ++mi)
#pragma unroll
    for (int ni = 0; ni < 4; ++ni) {
      const int col = col0 + wn * 64 + ni * 16 + l15;
      const int lcol = col & (D_ - 1);
      const float bv = bias ? bias[MODE == MODE_QKV ? lcol : col] : 0.0f;
#pragma unroll
      for (int r = 0; r < 4; ++r) {
        const int row = row0 + wm * 64 + mi * 16 + quad * 4 + r;
        const float val = acc[mi][ni][r] * alpha + bv;
        if (MODE == MODE_EXP) {
          C[(long)row * ldc + col] = (OutT)__expf(val);
        } else if (MODE == MODE_QKV) {
          C[grp * NX + (long)row * D_ + lcol] = (OutT)val;  // coalesced for all grps
        } else {
          C[(long)row * ldc + col] = (OutT)val;
        }
      }
    }
}

// grid (S, B): P[b,q,:] = E[b,q,:] * sum_m bit_m(q,:) / rowsum_m / M, bf16.
__global__ __launch_bounds__(256) void softmax_combine(
    const f16* __restrict__ E, const unsigned char* __restrict__ pk,
    bf16* __restrict__ P) {
  const int q = blockIdx.x;
  const int b = blockIdx.y;
  const int tid = threadIdx.x;
  const int lane = tid & 63;
  const int wv = tid >> 6;
  __shared__ float4 red[4];

  float e[8];
  {
    const f16x8 h = *(const f16x8*)(E + ((long)b * S_ + q) * S_ + tid * 8);
#pragma unroll
    for (int j = 0; j < 8; ++j) e[j] = (float)h[j];
  }
  const unsigned long long mb =
      *(const unsigned long long*)(pk + (long)q * S_ + tid * 8);

  float4 s = {0.f, 0.f, 0.f, 0.f};
#pragma unroll
  for (int j = 0; j < 8; ++j) {
    const unsigned bits = (unsigned)(mb >> (8 * j)) & 0xF;
    const float ev = e[j];
    if (bits & 1) s.x += ev;
    if (bits & 2) s.y += ev;
    if (bits & 4) s.z += ev;
    if (bits & 8) s.w += ev;
  }
#pragma unroll
  for (int o = 32; o > 0; o >>= 1) {
    s.x += __shfl_xor(s.x, o, 64);
    s.y += __shfl_xor(s.y, o, 64);
    s.z += __shfl_xor(s.z, o, 64);
    s.w += __shfl_xor(s.w, o, 64);
  }
  if (lane == 0) red[wv] = s;
  __syncthreads();
  const float4 t0 = red[0], t1 = red[1], t2 = red[2], t3 = red[3];
  const float r0 = 0.25f / (t0.x + t1.x + t2.x + t3.x);
  const float r1 = 0.25f / (t0.y + t1.y + t2.y + t3.y);
  const float r2 = 0.25f / (t0.z + t1.z + t2.z + t3.z);
  const float r3 = 0.25f / (t0.w + t1.w + t2.w + t3.w);

  bf16x8 o;
#pragma unroll
  for (int j = 0; j < 8; ++j) {
    const unsigned bits = (unsigned)(mb >> (8 * j)) & 0xF;
    const float wgt = ((bits & 1) ? r0 : 0.f) + ((bits & 2) ? r1 : 0.f) +
                      ((bits & 4) ? r2 : 0.f) + ((bits & 8) ? r3 : 0.f);
    o[j] = (bf16)(e[j] * wgt);
  }
  *(bf16x8*)(P + ((long)b * S_ + q) * S_ + tid * 8) = o;
}

extern "C" void kernel_launch(void* const* d_in, const int* in_sizes, int n_in,
                              void* d_out, int out_size, void* d_ws, size_t ws_size,
                              hipStream_t stream) {
  const float* x = (const float*)d_in[0];
  const int* masks = (const int*)d_in[1];
  const float* bq = (const float*)d_in[3];
  const float* bk = (const float*)d_in[5];
  const float* bv = (const float*)d_in[7];
  const float* bo = (const float*)d_in[9];
  float* out = (float*)d_out;

  const long DD = (long)D_ * D_;
  const long SD = (long)S_ * D_;
  const long NX = (long)B_ * SD;
  const long SS = (long)S_ * S_;

  // ws: xc 16M | WT 8M | Q 16M | K 16M | V 16M | VT 16M | P 32M | E 32M | pk 4M = 156 MiB
  bf16* xc = (bf16*)d_ws;
  bf16* WqT = xc + NX;  // WkT, WvT, WoT contiguous after
  bf16* WoT = WqT + 3 * DD;
  bf16* Q = WoT + DD;  // K = Q+NX, V = K+NX (contiguous: QKV epilogue relies on it)
  bf16* K = Q + NX;
  bf16* V = K + NX;
  bf16* VT = V + NX;
  bf16* P = VT + NX;                   // [B][S][S] bf16
  f16* E = (f16*)(P + (long)B_ * SS);  // [B][S][S] f16
  unsigned char* pk = (unsigned char*)(E + (long)B_ * SS);  // [S][S] u8
  bf16* attn = Q;                      // attn overwrites dead Q

  dim3 blk(256);

  convert_copy<<<dim3((uint32_t)(NX / 8 / 256)), blk, 0, stream>>>(x, xc, NX);
  transposeW4<<<dim3(16, 16, 4), blk, 0, stream>>>(
      (const float*)d_in[2], (const float*)d_in[4],
      (const float*)d_in[6], (const float*)d_in[8], WqT);
  pack_masks<<<dim3((uint32_t)(SS / 8 / 256)), blk, 0, stream>>>(masks, pk);

  // fused Q|K|V projection: [8192,1024] x [1024,3072], all coalesced writes
  gemm_bt<bf16, MODE_QKV><<<dim3(24, 64), blk, 0, stream>>>(
      xc, 0, D_, WqT, 0, D_, Q, 0, D_, bq, bk, bv, 1.0f, D_);

  // VT[b][d][s] = V[b][s][d]
  transposeB<<<dim3(16, 32, B_), blk, 0, stream>>>(V, VT, S_, D_, SD, SD);

  // E = exp(Q K^T / 32) : [B][2048][2048] f16, batched over z
  gemm_bt<f16, MODE_EXP><<<dim3(16, 16, B_), blk, 0, stream>>>(
      Q, SD, D_, K, SD, D_, E, SS, S_, nullptr, nullptr, nullptr, 1.0f / 32.0f, D_);

  // P = E * sum_m mask_m / rowsum_m / M
  softmax_combine<<<dim3(S_, B_), blk, 0, stream>>>(E, pk, P);

  // attn = P @ V : [B][2048][1024], K=2048, batched
  gemm_bt<bf16, MODE_PLAIN><<<dim3(8, 16, B_), blk, 0, stream>>>(
      P, SS, S_, VT, SD, S_, attn, SD, D_, nullptr, nullptr, nullptr, 1.0f, S_);

  // out = attn @ Wo + bo : fp32 epilogue straight to d_out
  gemm_bt<float, MODE_PLAIN><<<dim3(8, 64), blk, 0, stream>>>(
      attn, 0, D_, WoT, 0, D_, out, 0, D_, bo, nullptr, nullptr, 1.0f, D_);
}

// Round 9
// 404.351 us; speedup vs baseline: 1.4856x; 1.0219x over previous
//
#include <hip/hip_runtime.h>
#include <hip/hip_bf16.h>
#include <stdint.h>

#define B_ 4
#define S_ 2048
#define D_ 1024
#define M_ 4

typedef __bf16 bf16;
typedef _Float16 f16;
typedef unsigned char u8;
typedef __bf16 bf16x8 __attribute__((ext_vector_type(8)));
typedef _Float16 f16x8 __attribute__((ext_vector_type(8)));
typedef float f32x4 __attribute__((ext_vector_type(4)));

__device__ __forceinline__ void async_copy16(const void* g, void* l) {
  __builtin_amdgcn_global_load_lds(
      (const __attribute__((address_space(1))) void*)g,
      (__attribute__((address_space(3))) void*)l, 16, 0, 0);
}

// Fused prep, block ranges:
//   [0,4096)      : x fp32 -> bf16
//   [4096,5120)   : 4x W [1024,1024] fp32 -> WT bf16 (256 blocks each)
//   [5120,7168)   : pack 4 masks -> bitfield bytes
__global__ __launch_bounds__(256) void prep(
    const float* __restrict__ x, const float* __restrict__ w0,
    const float* __restrict__ w1, const float* __restrict__ w2,
    const float* __restrict__ w3, const int* __restrict__ masks,
    bf16* __restrict__ xc, bf16* __restrict__ WT, u8* __restrict__ pk) {
  __shared__ bf16 t[64][65];
  const int blk = blockIdx.x;
  const int tid = threadIdx.x;
  const long SS = (long)S_ * S_;

  if (blk < 4096) {  // x -> bf16
    const long i = (long)blk * 2048 + tid * 8;
    const float4 a = *(const float4*)(x + i);
    const float4 b = *(const float4*)(x + i + 4);
    bf16x8 o;
    o[0] = (bf16)a.x; o[1] = (bf16)a.y; o[2] = (bf16)a.z; o[3] = (bf16)a.w;
    o[4] = (bf16)b.x; o[5] = (bf16)b.y; o[6] = (bf16)b.z; o[7] = (bf16)b.w;
    *(bf16x8*)(xc + i) = o;
  } else if (blk < 5120) {  // weight transpose -> bf16
    const int local = blk - 4096;
    const int z = local >> 8;
    const int rem = local & 255;
    const int r0 = (rem >> 4) * 64;
    const int c0 = (rem & 15) * 64;
    const int tx = tid & 63;
    const int ty = tid >> 6;
    const float* in = (z == 0) ? w0 : (z == 1) ? w1 : (z == 2) ? w2 : w3;
    bf16* out = WT + (long)z * D_ * D_;
    for (int i = ty; i < 64; i += 4)
      t[i][tx] = (bf16)in[(long)(r0 + i) * D_ + c0 + tx];
    __syncthreads();
    for (int i = ty; i < 64; i += 4)
      out[(long)(c0 + i) * D_ + r0 + tx] = t[tx][i];
  } else {  // pack masks
    const long e = (long)(blk - 5120) * 2048 + tid * 8;
    unsigned long long wv = 0;
#pragma unroll
    for (int m = 0; m < M_; ++m) {
      const int4 a = *(const int4*)(masks + m * SS + e);
      const int4 b = *(const int4*)(masks + m * SS + e + 4);
      const int v[8] = {a.x, a.y, a.z, a.w, b.x, b.y, b.z, b.w};
#pragma unroll
      for (int j = 0; j < 8; ++j)
        wv |= (unsigned long long)(v[j] != 0 ? 1u : 0u) << (8 * j + m);
    }
    *(unsigned long long*)(pk + e) = wv;
  }
}

// batched bf16 [rows,cols] -> [cols,rows] transpose (z = batch)
__global__ __launch_bounds__(256) void transposeB(
    const bf16* __restrict__ in, bf16* __restrict__ out,
    int rows, int cols, long ib, long ob) {
  __shared__ bf16 t[64][65];
  in += (long)blockIdx.z * ib;
  out += (long)blockIdx.z * ob;
  const int r0 = blockIdx.y * 64;
  const int c0 = blockIdx.x * 64;
  const int tx = threadIdx.x & 63;
  const int ty = threadIdx.x >> 6;
#pragma unroll
  for (int i = ty; i < 64; i += 4) t[i][tx] = in[(long)(r0 + i) * cols + c0 + tx];
  __syncthreads();
#pragma unroll
  for (int i = ty; i < 64; i += 4) out[(long)(c0 + i) * rows + r0 + tx] = t[tx][i];
}

#define MODE_PLAIN 0
#define MODE_EXP 1   // C = exp(alpha*acc), f16 out (scores -> E)
#define MODE_QKV 2   // N=3072 grouped epilogue: Q | K | V, all coalesced

// C[m,n] = alpha*sum_k A[m,k]*Bt[n,k] + bias[n].  m97 structure: 128x128 tile,
// BK=64, global_load_lds w16, unpadded stride-64 LDS, 4 waves 2x2, 4x4 frags
// of mfma_f32_16x16x32_bf16. GROUP-8 M-swizzle for XCD L2 locality.
template <typename OutT, int MODE>
__global__ __launch_bounds__(256) void gemm_bt(
    const bf16* __restrict__ A, long aB, int lda,
    const bf16* __restrict__ Bt, long bB, int ldb,
    OutT* __restrict__ C, long cB, int ldc,
    const float* __restrict__ bias0, const float* __restrict__ bias1,
    const float* __restrict__ bias2, float alpha, int K) {
  __shared__ __align__(16) bf16 As[128 * 64];
  __shared__ __align__(16) bf16 Bs[128 * 64];
  const int tid = threadIdx.x;
  const int lane = tid & 63;
  const int w = tid >> 6;
  const int wm = w & 1;
  const int wn = w >> 1;
  A += (long)blockIdx.z * aB;
  Bt += (long)blockIdx.z * bB;
  if (MODE != MODE_QKV) C += (long)blockIdx.z * cB;

  // GROUP-8 swizzle (gy is always a multiple of 8 here)
  const int gx = gridDim.x;
  const int pid = blockIdx.y * gx + blockIdx.x;
  const int gsz = 8 * gx;
  const int bym = (pid / gsz) * 8 + (pid % 8);
  const int bxm = (pid % gsz) / 8;

  const int row0 = bym * 128;
  const int col0 = bxm * 128;
  const int quad = lane >> 4;
  const int l15 = lane & 15;
  const int srow = lane >> 3;       // 0..7 within the wave's 8-row chunk
  const int scol = (lane & 7) * 8;  // 8 bf16 = 16 B per lane

  f32x4 acc[4][4];
#pragma unroll
  for (int i = 0; i < 4; ++i)
#pragma unroll
    for (int j = 0; j < 4; ++j) acc[i][j] = (f32x4){0.f, 0.f, 0.f, 0.f};

  for (int kt = 0; kt < K; kt += 64) {
#pragma unroll
    for (int c = 0; c < 4; ++c) {
      const int r = c * 32 + w * 8;  // wave-uniform LDS base (8 rows = 1 KiB)
      async_copy16(A + (long)(row0 + r + srow) * lda + kt + scol, &As[r * 64]);
      async_copy16(Bt + (long)(col0 + r + srow) * ldb + kt + scol, &Bs[r * 64]);
    }
    __syncthreads();
#pragma unroll
    for (int ks = 0; ks < 2; ++ks) {
      bf16x8 af[4], bf[4];
#pragma unroll
      for (int i = 0; i < 4; ++i) {
        // A frag: A[m = lane&15][k = quad*8 + j]
        af[i] = *(const bf16x8*)&As[(wm * 64 + i * 16 + l15) * 64 + ks * 32 + quad * 8];
        bf[i] = *(const bf16x8*)&Bs[(wn * 64 + i * 16 + l15) * 64 + ks * 32 + quad * 8];
      }
#pragma unroll
      for (int mi = 0; mi < 4; ++mi)
#pragma unroll
        for (int ni = 0; ni < 4; ++ni)
          acc[mi][ni] = __builtin_amdgcn_mfma_f32_16x16x32_bf16(af[mi], bf[ni], acc[mi][ni], 0, 0, 0);
    }
    __syncthreads();
  }

  // QKV grouping block-uniform: cols 0-1023 -> Q, 1024-2047 -> K, 2048-3071 -> V
  const int grp = (MODE == MODE_QKV) ? (bxm >> 3) : 0;
  const float* bias = (MODE == MODE_QKV)
                          ? (grp == 0 ? bias0 : grp == 1 ? bias1 : bias2)
                          : bias0;
  const long NX = (long)B_ * S_ * D_;

  // C/D layout: col = lane&15 (n-side), row = quad*4 + reg (m-side)
#pragma unroll
  for (int mi = 0; mi < 4; ++mi)
#pragma unroll
    for (int ni = 0; ni < 4; ++ni) {
      const int col = col0 + wn * 64 + ni * 16 + l15;
      const int lcol = col & (D_ - 1);
      const float bv = bias ? bias[MODE == MODE_QKV ? lcol : col] : 0.0f;
#pragma unroll
      for (int r = 0; r < 4; ++r) {
        const int row = row0 + wm * 64 + mi * 16 + quad * 4 + r;
        const float val = acc[mi][ni][r] * alpha + bv;
        if (MODE == MODE_EXP) {
          C[(long)row * ldc + col] = (OutT)__expf(val);
        } else if (MODE == MODE_QKV) {
          C[grp * NX + (long)row * D_ + lcol] = (OutT)val;
        } else {
          C[(long)row * ldc + col] = (OutT)val;
        }
      }
    }
}

// grid (S, B): P[b,q,:] = E[b,q,:] * sum_m bit_m(q,:) / rowsum_m / M, bf16.
__global__ __launch_bounds__(256) void softmax_combine(
    const f16* __restrict__ E, const u8* __restrict__ pk, bf16* __restrict__ P) {
  const int q = blockIdx.x;
  const int b = blockIdx.y;
  const int tid = threadIdx.x;
  const int lane = tid & 63;
  const int wv = tid >> 6;
  __shared__ float4 red[4];

  float e[8];
  {
    const f16x8 h = *(const f16x8*)(E + ((long)b * S_ + q) * S_ + tid * 8);
#pragma unroll
    for (int j = 0; j < 8; ++j) e[j] = (float)h[j];
  }
  const unsigned long long mb =
      *(const unsigned long long*)(pk + (long)q * S_ + tid * 8);

  float4 s = {0.f, 0.f, 0.f, 0.f};
#pragma unroll
  for (int j = 0; j < 8; ++j) {
    const unsigned bits = (unsigned)(mb >> (8 * j)) & 0xF;
    const float ev = e[j];
    if (bits & 1) s.x += ev;
    if (bits & 2) s.y += ev;
    if (bits & 4) s.z += ev;
    if (bits & 8) s.w += ev;
  }
#pragma unroll
  for (int o = 32; o > 0; o >>= 1) {
    s.x += __shfl_xor(s.x, o, 64);
    s.y += __shfl_xor(s.y, o, 64);
    s.z += __shfl_xor(s.z, o, 64);
    s.w += __shfl_xor(s.w, o, 64);
  }
  if (lane == 0) red[wv] = s;
  __syncthreads();
  const float4 t0 = red[0], t1 = red[1], t2 = red[2], t3 = red[3];
  const float r0 = 0.25f / (t0.x + t1.x + t2.x + t3.x);
  const float r1 = 0.25f / (t0.y + t1.y + t2.y + t3.y);
  const float r2 = 0.25f / (t0.z + t1.z + t2.z + t3.z);
  const float r3 = 0.25f / (t0.w + t1.w + t2.w + t3.w);

  bf16x8 o;
#pragma unroll
  for (int j = 0; j < 8; ++j) {
    const unsigned bits = (unsigned)(mb >> (8 * j)) & 0xF;
    const float wgt = ((bits & 1) ? r0 : 0.f) + ((bits & 2) ? r1 : 0.f) +
                      ((bits & 4) ? r2 : 0.f) + ((bits & 8) ? r3 : 0.f);
    o[j] = (bf16)(e[j] * wgt);
  }
  *(bf16x8*)(P + ((long)b * S_ + q) * S_ + tid * 8) = o;
}

extern "C" void kernel_launch(void* const* d_in, const int* in_sizes, int n_in,
                              void* d_out, int out_size, void* d_ws, size_t ws_size,
                              hipStream_t stream) {
  const float* x = (const float*)d_in[0];
  const int* masks = (const int*)d_in[1];
  const float* bq = (const float*)d_in[3];
  const float* bk = (const float*)d_in[5];
  const float* bv = (const float*)d_in[7];
  const float* bo = (const float*)d_in[9];
  float* out = (float*)d_out;

  const long DD = (long)D_ * D_;
  const long SD = (long)S_ * D_;
  const long NX = (long)B_ * SD;
  const long SS = (long)S_ * S_;

  // ws: xc 16M | WT 8M | pk 4M | Q/K/V 48M | VT 16M | P 32M | E 32M = 156 MiB
  bf16* xc = (bf16*)d_ws;
  bf16* WqT = xc + NX;  // WkT, WvT, WoT contiguous after
  bf16* WoT = WqT + 3 * DD;
  u8* pk = (u8*)(WoT + DD);    // [S][S] mask bitfield
  bf16* Q = (bf16*)(pk + SS);  // K = Q+NX, V = K+NX (QKV epilogue relies on it)
  bf16* K = Q + NX;
  bf16* V = K + NX;
  bf16* VT = V + NX;
  bf16* P = VT + NX;                   // [B][S][S] bf16
  f16* E = (f16*)(P + (long)B_ * SS);  // [B][S][S] f16
  bf16* attn = Q;                      // attn overwrites dead Q

  dim3 blk(256);

  // fused prep: x->bf16, 4 weight transposes, mask pack (one launch)
  prep<<<dim3(7168), blk, 0, stream>>>(
      x, (const float*)d_in[2], (const float*)d_in[4], (const float*)d_in[6],
      (const float*)d_in[8], masks, xc, WqT, pk);

  // fused Q|K|V projection: [8192,1024] x [1024,3072], all coalesced writes
  gemm_bt<bf16, MODE_QKV><<<dim3(24, 64), blk, 0, stream>>>(
      xc, 0, D_, WqT, 0, D_, Q, 0, D_, bq, bk, bv, 1.0f, D_);

  // VT[b][d][s] = V[b][s][d]
  transposeB<<<dim3(16, 32, B_), blk, 0, stream>>>(V, VT, S_, D_, SD, SD);

  // E = exp(Q K^T / 32) : [B][2048][2048] f16, batched over z
  gemm_bt<f16, MODE_EXP><<<dim3(16, 16, B_), blk, 0, stream>>>(
      Q, SD, D_, K, SD, D_, E, SS, S_, nullptr, nullptr, nullptr, 1.0f / 32.0f, D_);

  // P = E * sum_m mask_m / rowsum_m / M
  softmax_combine<<<dim3(S_, B_), blk, 0, stream>>>(E, pk, P);

  // attn = P @ V : [B][2048][1024], K=2048, batched
  gemm_bt<bf16, MODE_PLAIN><<<dim3(8, 16, B_), blk, 0, stream>>>(
      P, SS, S_, VT, SD, S_, attn, SD, D_, nullptr, nullptr, nullptr, 1.0f, S_);

  // out = attn @ Wo + bo : fp32 epilogue straight to d_out
  gemm_bt<float, MODE_PLAIN><<<dim3(8, 64), blk, 0, stream>>>(
      attn, 0, D_, WoT, 0, D_, out, 0, D_, bo, nullptr, nullptr, 1.0f, D_);
}

// Round 11
// 397.744 us; speedup vs baseline: 1.5103x; 1.0166x over previous
//
#include <hip/hip_runtime.h>
#include <hip/hip_bf16.h>
#include <stdint.h>

#define B_ 4
#define S_ 2048
#define D_ 1024
#define M_ 4

typedef __bf16 bf16;
typedef _Float16 f16;
typedef unsigned char u8;
typedef __bf16 bf16x8 __attribute__((ext_vector_type(8)));
typedef _Float16 f16x8 __attribute__((ext_vector_type(8)));
typedef float f32x4 __attribute__((ext_vector_type(4)));

__device__ __forceinline__ void async_copy16(const void* g, void* l) {
  __builtin_amdgcn_global_load_lds(
      (const __attribute__((address_space(1))) void*)g,
      (__attribute__((address_space(3))) void*)l, 16, 0, 0);
}

// Fused prep, block ranges:
//   [0,4096)      : x fp32 -> bf16
//   [4096,5120)   : 4x W [1024,1024] fp32 -> WT bf16 (256 blocks each)
//   [5120,7168)   : pack 4 masks -> bitfield bytes
__global__ __launch_bounds__(256) void prep(
    const float* __restrict__ x, const float* __restrict__ w0,
    const float* __restrict__ w1, const float* __restrict__ w2,
    const float* __restrict__ w3, const int* __restrict__ masks,
    bf16* __restrict__ xc, bf16* __restrict__ WT, u8* __restrict__ pk) {
  __shared__ bf16 t[64][65];
  const int blk = blockIdx.x;
  const int tid = threadIdx.x;
  const long SS = (long)S_ * S_;

  if (blk < 4096) {  // x -> bf16
    const long i = (long)blk * 2048 + tid * 8;
    const float4 a = *(const float4*)(x + i);
    const float4 b = *(const float4*)(x + i + 4);
    bf16x8 o;
    o[0] = (bf16)a.x; o[1] = (bf16)a.y; o[2] = (bf16)a.z; o[3] = (bf16)a.w;
    o[4] = (bf16)b.x; o[5] = (bf16)b.y; o[6] = (bf16)b.z; o[7] = (bf16)b.w;
    *(bf16x8*)(xc + i) = o;
  } else if (blk < 5120) {  // weight transpose -> bf16
    const int local = blk - 4096;
    const int z = local >> 8;
    const int rem = local & 255;
    const int r0 = (rem >> 4) * 64;
    const int c0 = (rem & 15) * 64;
    const int tx = tid & 63;
    const int ty = tid >> 6;
    const float* in = (z == 0) ? w0 : (z == 1) ? w1 : (z == 2) ? w2 : w3;
    bf16* out = WT + (long)z * D_ * D_;
    for (int i = ty; i < 64; i += 4)
      t[i][tx] = (bf16)in[(long)(r0 + i) * D_ + c0 + tx];
    __syncthreads();
    for (int i = ty; i < 64; i += 4)
      out[(long)(c0 + i) * D_ + r0 + tx] = t[tx][i];
  } else {  // pack masks
    const long e = (long)(blk - 5120) * 2048 + tid * 8;
    unsigned long long wv = 0;
#pragma unroll
    for (int m = 0; m < M_; ++m) {
      const int4 a = *(const int4*)(masks + m * SS + e);
      const int4 b = *(const int4*)(masks + m * SS + e + 4);
      const int v[8] = {a.x, a.y, a.z, a.w, b.x, b.y, b.z, b.w};
#pragma unroll
      for (int j = 0; j < 8; ++j)
        wv |= (unsigned long long)(v[j] != 0 ? 1u : 0u) << (8 * j + m);
    }
    *(unsigned long long*)(pk + e) = wv;
  }
}

// batched bf16 [rows,cols] -> [cols,rows] transpose (z = batch)
__global__ __launch_bounds__(256) void transposeB(
    const bf16* __restrict__ in, bf16* __restrict__ out,
    int rows, int cols, long ib, long ob) {
  __shared__ bf16 t[64][65];
  in += (long)blockIdx.z * ib;
  out += (long)blockIdx.z * ob;
  const int r0 = blockIdx.y * 64;
  const int c0 = blockIdx.x * 64;
  const int tx = threadIdx.x & 63;
  const int ty = threadIdx.x >> 6;
#pragma unroll
  for (int i = ty; i < 64; i += 4) t[i][tx] = in[(long)(r0 + i) * cols + c0 + tx];
  __syncthreads();
#pragma unroll
  for (int i = ty; i < 64; i += 4) out[(long)(c0 + i) * rows + r0 + tx] = t[tx][i];
}

#define MODE_PLAIN 0
#define MODE_EXP 1   // C = exp(alpha*acc), f16 out (scores -> E)
#define MODE_QKV 2   // N=3072 grouped epilogue: Q | K | V, all coalesced

// C[m,n] = alpha*sum_k A[m,k]*Bt[n,k] + bias[n].
// 128x128 tile, BK=64, global_load_lds w16, SINGLE-BARRIER double-buffered
// K-loop (prefetch for step i+1 issued right after the barrier that drains
// step i's DMA -> prefetch gets a full compute phase to land). 64 KB LDS,
// 2 blocks/CU. GROUP-16 M-swizzle for XCD L2 locality.
template <typename OutT, int MODE>
__global__ __launch_bounds__(256) void gemm_bt(
    const bf16* __restrict__ A, long aB, int lda,
    const bf16* __restrict__ Bt, long bB, int ldb,
    OutT* __restrict__ C, long cB, int ldc,
    const float* __restrict__ bias0, const float* __restrict__ bias1,
    const float* __restrict__ bias2, float alpha, int K) {
  __shared__ __align__(16) bf16 As[2][128 * 64];
  __shared__ __align__(16) bf16 Bs[2][128 * 64];
  const int tid = threadIdx.x;
  const int lane = tid & 63;
  const int w = tid >> 6;
  const int wm = w & 1;
  const int wn = w >> 1;
  A += (long)blockIdx.z * aB;
  Bt += (long)blockIdx.z * bB;
  if (MODE != MODE_QKV) C += (long)blockIdx.z * cB;

  // GROUP-16 swizzle (gy is a multiple of 16 in all our launches)
  const int gx = gridDim.x;
  const int pid = blockIdx.y * gx + blockIdx.x;
  const int gsz = 16 * gx;
  const int bym = (pid / gsz) * 16 + (pid % 16);
  const int bxm = (pid % gsz) / 16;

  const int row0 = bym * 128;
  const int col0 = bxm * 128;
  const int quad = lane >> 4;
  const int l15 = lane & 15;
  const int srow = lane >> 3;       // 0..7 within the wave's 8-row chunk
  const int scol = (lane & 7) * 8;  // 8 bf16 = 16 B per lane

  f32x4 acc[4][4];
#pragma unroll
  for (int i = 0; i < 4; ++i)
#pragma unroll
    for (int j = 0; j < 4; ++j) acc[i][j] = (f32x4){0.f, 0.f, 0.f, 0.f};

  const int nk = K >> 6;

  // prologue: stage tile 0 into buffer 0
#pragma unroll
  for (int c = 0; c < 4; ++c) {
    const int r = c * 32 + w * 8;
    async_copy16(A + (long)(row0 + r + srow) * lda + scol, &As[0][r * 64]);
    async_copy16(Bt + (long)(col0 + r + srow) * ldb + scol, &Bs[0][r * 64]);
  }

  for (int i = 0; i < nk; ++i) {
    const int cur = i & 1;
    __syncthreads();  // drains DMA for buf[cur]; orders prior reads of buf[cur^1]
    if (i + 1 < nk) {
      const int kt = (i + 1) << 6;
      const int nxt = cur ^ 1;
#pragma unroll
      for (int c = 0; c < 4; ++c) {
        const int r = c * 32 + w * 8;
        async_copy16(A + (long)(row0 + r + srow) * lda + kt + scol, &As[nxt][r * 64]);
        async_copy16(Bt + (long)(col0 + r + srow) * ldb + kt + scol, &Bs[nxt][r * 64]);
      }
    }
#pragma unroll
    for (int ks = 0; ks < 2; ++ks) {
      bf16x8 af[4], bf[4];
#pragma unroll
      for (int j = 0; j < 4; ++j) {
        // A frag: A[m = lane&15][k = quad*8 + j]
        af[j] = *(const bf16x8*)&As[cur][(wm * 64 + j * 16 + l15) * 64 + ks * 32 + quad * 8];
        bf[j] = *(const bf16x8*)&Bs[cur][(wn * 64 + j * 16 + l15) * 64 + ks * 32 + quad * 8];
      }
#pragma unroll
      for (int mi = 0; mi < 4; ++mi)
#pragma unroll
        for (int ni = 0; ni < 4; ++ni)
          acc[mi][ni] = __builtin_amdgcn_mfma_f32_16x16x32_bf16(af[mi], bf[ni], acc[mi][ni], 0, 0, 0);
    }
  }

  // QKV grouping block-uniform: cols 0-1023 -> Q, 1024-2047 -> K, 2048-3071 -> V
  const int grp = (MODE == MODE_QKV) ? (bxm >> 3) : 0;
  const float* bias = (MODE == MODE_QKV)
                          ? (grp == 0 ? bias0 : grp == 1 ? bias1 : bias2)
                          : bias0;
  const long NX = (long)B_ * S_ * D_;

  // C/D layout: col = lane&15 (n-side), row = quad*4 + reg (m-side)
#pragma unroll
  for (int mi = 0; mi < 4; ++mi)
#pragma unroll
    for (int ni = 0; ni < 4; ++ni) {
      const int col = col0 + wn * 64 + ni * 16 + l15;
      const int lcol = col & (D_ - 1);
      const float bv = bias ? bias[MODE == MODE_QKV ? lcol : col] : 0.0f;
#pragma unroll
      for (int r = 0; r < 4; ++r) {
        const int row = row0 + wm * 64 + mi * 16 + quad * 4 + r;
        const float val = acc[mi][ni][r] * alpha + bv;
        if (MODE == MODE_EXP) {
          C[(long)row * ldc + col] = (OutT)__expf(val);
        } else if (MODE == MODE_QKV) {
          C[grp * NX + (long)row * D_ + lcol] = (OutT)val;
        } else {
          C[(long)row * ldc + col] = (OutT)val;
        }
      }
    }
}

// grid (S, B): P[b,q,:] = E[b,q,:] * sum_m bit_m(q,:) / rowsum_m / M, bf16.
__global__ __launch_bounds__(256) void softmax_combine(
    const f16* __restrict__ E, const u8* __restrict__ pk, bf16* __restrict__ P) {
  const int q = blockIdx.x;
  const int b = blockIdx.y;
  const int tid = threadIdx.x;
  const int lane = tid & 63;
  const int wv = tid >> 6;
  __shared__ float4 red[4];

  float e[8];
  {
    const f16x8 h = *(const f16x8*)(E + ((long)b * S_ + q) * S_ + tid * 8);
#pragma unroll
    for (int j = 0; j < 8; ++j) e[j] = (float)h[j];
  }
  const unsigned long long mb =
      *(const unsigned long long*)(pk + (long)q * S_ + tid * 8);

  float4 s = {0.f, 0.f, 0.f, 0.f};
#pragma unroll
  for (int j = 0; j < 8; ++j) {
    const unsigned bits = (unsigned)(mb >> (8 * j)) & 0xF;
    const float ev = e[j];
    if (bits & 1) s.x += ev;
    if (bits & 2) s.y += ev;
    if (bits & 4) s.z += ev;
    if (bits & 8) s.w += ev;
  }
#pragma unroll
  for (int o = 32; o > 0; o >>= 1) {
    s.x += __shfl_xor(s.x, o, 64);
    s.y += __shfl_xor(s.y, o, 64);
    s.z += __shfl_xor(s.z, o, 64);
    s.w += __shfl_xor(s.w, o, 64);
  }
  if (lane == 0) red[wv] = s;
  __syncthreads();
  const float4 t0 = red[0], t1 = red[1], t2 = red[2], t3 = red[3];
  const float r0 = 0.25f / (t0.x + t1.x + t2.x + t3.x);
  const float r1 = 0.25f / (t0.y + t1.y + t2.y + t3.y);
  const float r2 = 0.25f / (t0.z + t1.z + t2.z + t3.z);
  const float r3 = 0.25f / (t0.w + t1.w + t2.w + t3.w);

  bf16x8 o;
#pragma unroll
  for (int j = 0; j < 8; ++j) {
    const unsigned bits = (unsigned)(mb >> (8 * j)) & 0xF;
    const float wgt = ((bits & 1) ? r0 : 0.f) + ((bits & 2) ? r1 : 0.f) +
                      ((bits & 4) ? r2 : 0.f) + ((bits & 8) ? r3 : 0.f);
    o[j] = (bf16)(e[j] * wgt);
  }
  *(bf16x8*)(P + ((long)b * S_ + q) * S_ + tid * 8) = o;
}

extern "C" void kernel_launch(void* const* d_in, const int* in_sizes, int n_in,
                              void* d_out, int out_size, void* d_ws, size_t ws_size,
                              hipStream_t stream) {
  const float* x = (const float*)d_in[0];
  const int* masks = (const int*)d_in[1];
  const float* bq = (const float*)d_in[3];
  const float* bk = (const float*)d_in[5];
  const float* bv = (const float*)d_in[7];
  const float* bo = (const float*)d_in[9];
  float* out = (float*)d_out;

  const long DD = (long)D_ * D_;
  const long SD = (long)S_ * D_;
  const long NX = (long)B_ * SD;
  const long SS = (long)S_ * S_;

  // ws: xc 16M | WT 8M | pk 4M | Q/K/V 48M | VT 16M | P 32M | E 32M = 156 MiB
  bf16* xc = (bf16*)d_ws;
  bf16* WqT = xc + NX;  // WkT, WvT, WoT contiguous after
  bf16* WoT = WqT + 3 * DD;
  u8* pk = (u8*)(WoT + DD);    // [S][S] mask bitfield
  bf16* Q = (bf16*)(pk + SS);  // K = Q+NX, V = K+NX (QKV epilogue relies on it)
  bf16* K = Q + NX;
  bf16* V = K + NX;
  bf16* VT = V + NX;
  bf16* P = VT + NX;                   // [B][S][S] bf16
  f16* E = (f16*)(P + (long)B_ * SS);  // [B][S][S] f16
  bf16* attn = Q;                      // attn overwrites dead Q

  dim3 blk(256);

  // fused prep: x->bf16, 4 weight transposes, mask pack (one launch)
  prep<<<dim3(7168), blk, 0, stream>>>(
      x, (const float*)d_in[2], (const float*)d_in[4], (const float*)d_in[6],
      (const float*)d_in[8], masks, xc, WqT, pk);

  // fused Q|K|V projection: [8192,1024] x [1024,3072], all coalesced writes
  gemm_bt<bf16, MODE_QKV><<<dim3(24, 64), blk, 0, stream>>>(
      xc, 0, D_, WqT, 0, D_, Q, 0, D_, bq, bk, bv, 1.0f, D_);

  // VT[b][d][s] = V[b][s][d]
  transposeB<<<dim3(16, 32, B_), blk, 0, stream>>>(V, VT, S_, D_, SD, SD);

  // E = exp(Q K^T / 32) : [B][2048][2048] f16, batched over z
  gemm_bt<f16, MODE_EXP><<<dim3(16, 16, B_), blk, 0, stream>>>(
      Q, SD, D_, K, SD, D_, E, SS, S_, nullptr, nullptr, nullptr, 1.0f / 32.0f, D_);

  // P = E * sum_m mask_m / rowsum_m / M
  softmax_combine<<<dim3(S_, B_), blk, 0, stream>>>(E, pk, P);

  // attn = P @ V : [B][2048][1024], K=2048, batched
  gemm_bt<bf16, MODE_PLAIN><<<dim3(8, 16, B_), blk, 0, stream>>>(
      P, SS, S_, VT, SD, S_, attn, SD, D_, nullptr, nullptr, nullptr, 1.0f, S_);

  // out = attn @ Wo + bo : fp32 epilogue straight to d_out
  gemm_bt<float, MODE_PLAIN><<<dim3(8, 64), blk, 0, stream>>>(
      attn, 0, D_, WoT, 0, D_, out, 0, D_, bo, nullptr, nullptr, 1.0f, D_);
}